// Round 5
// baseline (976.976 us; speedup 1.0000x reference)
//
#include <hip/hip_runtime.h>

#define DF   128    // feature dim
#define EPB  1024   // elements per scan block
#define MAXB 512    // max level-2 scan width (supports M <= 524288)
#define TB   128    // nodes per block in fused kernel
#define RPW  32     // rows per wave (TB / 4 waves)

typedef __attribute__((ext_vector_type(8))) short short8;
typedef __attribute__((ext_vector_type(4))) float f32x4;

__device__ __forceinline__ unsigned short f2bf(float x) {
    unsigned u = __float_as_uint(x);
    u = (u + 0x7FFFu + ((u >> 16) & 1u)) >> 16;   // RNE
    return (unsigned short)u;
}
__device__ __forceinline__ unsigned pack2bf(float a, float b) {
    return (unsigned)f2bf(a) | ((unsigned)f2bf(b) << 16);
}

// ===========================================================================
// CSR build: count degrees -> exclusive scan -> place edge ids.
// Node space M = [66: 0..N6) [86: N6..2N6) [68: 2N6..2N6+N8) [88: ...+N8)
// Edge space  = [66: 0..E66) [86 ...) [68 ...) [88 ...)  (global gid)
// ===========================================================================

__global__ void __launch_bounds__(256) count_kernel(
    const int* __restrict__ ei66, const int* __restrict__ ei86,
    const int* __restrict__ ei68, const int* __restrict__ ei88,
    int E66, int E86, int E68, int E88, int N6, int N8,
    int* __restrict__ base)
{
    int Etot = E66 + E86 + E68 + E88;
    for (int gid = blockIdx.x * 256 + threadIdx.x; gid < Etot;
         gid += gridDim.x * 256) {
        int le = gid, nb, dst;
        if (le < E66)               { dst = ei66[2 * le + 1]; nb = 0; }
        else if ((le -= E66) < E86) { dst = ei86[2 * le + 1]; nb = N6; }
        else if ((le -= E86) < E68) { dst = ei68[2 * le + 1]; nb = 2 * N6; }
        else { le -= E68;             dst = ei88[2 * le + 1]; nb = 2 * N6 + N8; }
        atomicAdd(base + nb + dst, 1);
    }
}

__global__ void __launch_bounds__(256) scan1_kernel(
    int* __restrict__ data, int M, int* __restrict__ bsum)
{
    __shared__ int ts[256];
    int t = threadIdx.x;
    int i0 = blockIdx.x * EPB + t * 4;
    int v0 = 0, v1 = 0, v2 = 0, v3 = 0;
    if (i0 + 3 < M) {
        int4 q = *(const int4*)(data + i0);
        v0 = q.x; v1 = q.y; v2 = q.z; v3 = q.w;
    } else {
        if (i0     < M) v0 = data[i0];
        if (i0 + 1 < M) v1 = data[i0 + 1];
        if (i0 + 2 < M) v2 = data[i0 + 2];
    }
    int sum = v0 + v1 + v2 + v3;
    ts[t] = sum;
    __syncthreads();
    for (int off = 1; off < 256; off <<= 1) {
        int x = (t >= off) ? ts[t - off] : 0;
        __syncthreads();
        ts[t] += x;
        __syncthreads();
    }
    int excl = ts[t] - sum;
    if (t == 255) bsum[blockIdx.x] = ts[255];
    int w0 = excl, w1 = excl + v0, w2 = w1 + v1, w3 = w2 + v2;
    if (i0 + 3 < M) {
        *(int4*)(data + i0) = make_int4(w0, w1, w2, w3);
    } else {
        if (i0     < M) data[i0]     = w0;
        if (i0 + 1 < M) data[i0 + 1] = w1;
        if (i0 + 2 < M) data[i0 + 2] = w2;
    }
}

__global__ void __launch_bounds__(256) scan2_kernel(int* __restrict__ bsum, int nb)
{
    __shared__ int s[MAXB];
    int t = threadIdx.x;
    s[t]       = (t       < nb) ? bsum[t]       : 0;
    s[t + 256] = (t + 256 < nb) ? bsum[t + 256] : 0;
    __syncthreads();
    int o0 = s[t], o1 = s[t + 256];
    for (int off = 1; off < MAXB; off <<= 1) {
        int a = (t       >= off) ? s[t       - off] : 0;
        int b = (t + 256 >= off) ? s[t + 256 - off] : 0;
        __syncthreads();
        s[t] += a; s[t + 256] += b;
        __syncthreads();
    }
    if (t       < nb) bsum[t]       = s[t]       - o0;
    if (t + 256 < nb) bsum[t + 256] = s[t + 256] - o1;
}

__global__ void __launch_bounds__(256) scan3_kernel(
    int* __restrict__ data, int M, const int* __restrict__ bsum)
{
    int add = bsum[blockIdx.x];
    if (add == 0) return;
    int i0 = blockIdx.x * EPB + threadIdx.x * 4;
    if (i0 + 3 < M) {
        int4 q = *(const int4*)(data + i0);
        q.x += add; q.y += add; q.z += add; q.w += add;
        *(int4*)(data + i0) = q;
    } else {
        if (i0     < M) data[i0]     += add;
        if (i0 + 1 < M) data[i0 + 1] += add;
        if (i0 + 2 < M) data[i0 + 2] += add;
    }
}

__global__ void __launch_bounds__(256) fill_kernel(
    const int* __restrict__ ei66, const int* __restrict__ ei86,
    const int* __restrict__ ei68, const int* __restrict__ ei88,
    int E66, int E86, int E68, int E88, int N6, int N8,
    int* __restrict__ base, int* __restrict__ csr)
{
    int Etot = E66 + E86 + E68 + E88;
    for (int gid = blockIdx.x * 256 + threadIdx.x; gid < Etot;
         gid += gridDim.x * 256) {
        int le = gid, nb, dst;
        if (le < E66)               { dst = ei66[2 * le + 1]; nb = 0; }
        else if ((le -= E66) < E86) { dst = ei86[2 * le + 1]; nb = N6; }
        else if ((le -= E86) < E68) { dst = ei68[2 * le + 1]; nb = 2 * N6; }
        else { le -= E68;             dst = ei88[2 * le + 1]; nb = 2 * N6 + N8; }
        int pos = atomicAdd(base + nb + dst, 1);
        csr[pos] = gid;
    }
}

// ===========================================================================
// Fused gather-sum (f32 regs) -> bf16 LDS A-tile -> MFMA with bf16 W^T -> mean.
// Block = 128 nodes, 4 waves x 32 rows. Flat CSR slot walk per wave (all lanes
// always active; loads batched 8-wide). A and W^T tiles XOR-swizzled at 16B
// chunk granularity for conflict-free ds_read_b128.
// After fill: start(g) = g ? base[g-1] : 0, end(g) = base[g] (cumulative).
// ===========================================================================
__global__ void __launch_bounds__(256, 2) gather_mfma_kernel(
    const float* __restrict__ msg, const float* __restrict__ Wm,
    const int* __restrict__ base, const int* __restrict__ csr,
    int gbase, int ebase, float* __restrict__ out, int N)
{
    __shared__ alignas(16) short Atile[TB * DF];   // 32 KB bf16 sums (swizzled)
    __shared__ alignas(16) short Wt[DF * DF];      // 32 KB bf16 W^T (swizzled)
    __shared__ float invd[TB];
    __shared__ int   ends[TB + 1];

    const int t    = threadIdx.x;
    const int lane = t & 63;
    const int w    = t >> 6;
    const int n0   = blockIdx.x * TB;

    // ends[i] = end-slot of node (n0+i-1); ends[0] = start slot of node n0.
    // OOB rows clamp to N-1 -> empty ranges.
    for (int i = t; i <= TB; i += 256) {
        int idx = n0 + i - 1;
        if (idx >= N) idx = N - 1;
        int g = gbase + idx;
        ends[i] = (g >= 0) ? base[g] : 0;
    }

    // stage W^T as bf16, swizzled: Wt row n holds W[k][n] along k;
    // element k at short index n*DF + ((k>>3)^(n&7))*8 + (k&7)
    for (int i = t * 4; i < DF * DF; i += 1024) {
        float4 w4 = *(const float4*)(Wm + i);
        int k = i >> 7, n = i & (DF - 1);
        float wv[4] = {w4.x, w4.y, w4.z, w4.w};
        #pragma unroll
        for (int j = 0; j < 4; ++j) {
            int nn = n + j;
            int chunk = (k >> 3) ^ (nn & 7);
            Wt[nn * DF + chunk * 8 + (k & 7)] = (short)f2bf(wv[j]);
        }
    }
    __syncthreads();

    // ---------------- gather-sum phase ----------------
    const int wrow0 = w * RPW;
    int s        = ends[wrow0];
    const int s1 = ends[wrow0 + RPW];
    int row   = 0;
    int stcur = s;
    int nend  = ends[wrow0 + 1];
    float ax = 0.f, ay = 0.f;   // lane owns feature cols 2*lane, 2*lane+1

    while (true) {
        // flush completed (or empty / OOB) rows at current slot position
        while (row < RPW && s == nend) {
            int m = wrow0 + row;
            int deg = nend - stcur;
            *(unsigned*)(Atile + m * DF + (((lane >> 2) ^ (m & 7)) * 8)
                         + (lane & 3) * 2) = pack2bf(ax, ay);
            if (lane == 0) invd[m] = (deg > 0) ? (1.0f / (float)deg) : 0.0f;
            ax = 0.f; ay = 0.f;
            ++row; stcur = nend;
            nend = (row < RPW) ? ends[wrow0 + row + 1] : -1;
        }
        if (row >= RPW) break;

        int nld = s1 - s; if (nld > 8) nld = 8;   // >=1 here (s < nend <= s1)
        int e[8]; float2 v[8];
        #pragma unroll
        for (int j = 0; j < 8; ++j)
            e[j] = (j < nld) ? csr[s + j] : 0;
        #pragma unroll
        for (int j = 0; j < 8; ++j)
            if (j < nld)
                v[j] = ((const float2*)(msg + (size_t)(e[j] - ebase) * DF))[lane];
        #pragma unroll
        for (int j = 0; j < 8; ++j) {
            if (j < nld) {
                while (s + j == nend) {   // boundary: flush before consuming
                    int m = wrow0 + row;
                    int deg = nend - stcur;
                    *(unsigned*)(Atile + m * DF + (((lane >> 2) ^ (m & 7)) * 8)
                                 + (lane & 3) * 2) = pack2bf(ax, ay);
                    if (lane == 0) invd[m] = (deg > 0) ? (1.0f/(float)deg) : 0.0f;
                    ax = 0.f; ay = 0.f;
                    ++row; stcur = nend;
                    nend = (row < RPW) ? ends[wrow0 + row + 1] : -1;
                }
                ax += v[j].x; ay += v[j].y;
            }
        }
        s += nld;
    }
    __syncthreads();

    // ---------------- MFMA phase ----------------
    // wave w computes row-tiles {2w, 2w+1} x all 8 col-tiles.
    // A(m,k): m=lane&15, k=(lane>>4)*8+j ; B(k,n): n=lane&15, same k.
    // D: col=lane&15, row=(lane>>4)*4+reg.
    f32x4 acc[2][8];
    #pragma unroll
    for (int i = 0; i < 2; ++i)
        #pragma unroll
        for (int j = 0; j < 8; ++j)
            acc[i][j] = (f32x4){0.f, 0.f, 0.f, 0.f};

    const int l15 = lane & 15;
    const int lg  = lane >> 4;

    #pragma unroll
    for (int kk = 0; kk < 4; ++kk) {
        short8 av[2];
        #pragma unroll
        for (int i = 0; i < 2; ++i) {
            int m = (2 * w + i) * 16 + l15;
            int chunk = (kk * 4 + lg) ^ (m & 7);
            av[i] = *(const short8*)(Atile + m * DF + chunk * 8);
        }
        #pragma unroll
        for (int j = 0; j < 8; ++j) {
            int n = j * 16 + l15;
            int chunk = (kk * 4 + lg) ^ (n & 7);
            short8 bv = *(const short8*)(Wt + n * DF + chunk * 8);
            #pragma unroll
            for (int i = 0; i < 2; ++i)
                acc[i][j] = __builtin_amdgcn_mfma_f32_16x16x32_bf16(
                    av[i], bv, acc[i][j], 0, 0, 0);
        }
    }

    // ---------------- epilogue: mean + store ----------------
    #pragma unroll
    for (int i = 0; i < 2; ++i) {
        #pragma unroll
        for (int q = 0; q < 4; ++q) {
            int lrow = (2 * w + i) * 16 + lg * 4 + q;
            float iv = invd[lrow];
            int node = n0 + lrow;
            if (node < N) {
                float* op = out + (size_t)node * 256;
                #pragma unroll
                for (int j = 0; j < 8; ++j)
                    op[j * 16 + l15] = acc[i][j][q] * iv;
            }
        }
    }
}

// masks from post-fill base diffs: num_types = (deg_a>0) + (deg_b>0)
__global__ void __launch_bounds__(256) mask_kernel(
    const int* __restrict__ base, float* __restrict__ nt6,
    float* __restrict__ nt8, int N6, int N8)
{
    int i = blockIdx.x * blockDim.x + threadIdx.x;
    if (i < N6) {
        int g66 = i, g86 = N6 + i;
        int d66 = base[g66] - (g66 ? base[g66 - 1] : 0);
        int d86 = base[g86] - base[g86 - 1];
        nt6[i] = (float)((d66 > 0) + (d86 > 0));
    }
    if (i < N8) {
        int g68 = 2 * N6 + i, g88 = 2 * N6 + N8 + i;
        int d68 = base[g68] - base[g68 - 1];
        int d88 = base[g88] - base[g88 - 1];
        nt8[i] = (float)((d68 > 0) + (d88 > 0));
    }
}

extern "C" void kernel_launch(void* const* d_in, const int* in_sizes, int n_in,
                              void* d_out, int out_size, void* d_ws, size_t ws_size,
                              hipStream_t stream)
{
    const float* msg66 = (const float*)d_in[0];
    const float* msg68 = (const float*)d_in[1];
    const float* msg86 = (const float*)d_in[2];
    const float* msg88 = (const float*)d_in[3];
    const float* W66   = (const float*)d_in[4];
    const float* W68   = (const float*)d_in[5];
    const float* W86   = (const float*)d_in[6];
    const float* W88   = (const float*)d_in[7];
    const int*   ei66  = (const int*)d_in[8];
    const int*   ei68  = (const int*)d_in[9];
    const int*   ei86  = (const int*)d_in[10];
    const int*   ei88  = (const int*)d_in[11];

    int E66 = in_sizes[8]  / 2;
    int E68 = in_sizes[9]  / 2;
    int E86 = in_sizes[10] / 2;
    int E88 = in_sizes[11] / 2;
    int Etot = E66 + E86 + E68 + E88;

    size_t S  = (size_t)out_size / 257;       // out = 257*(N6+N8)
    int    N6 = (int)(S / 2);
    int    N8 = (int)(S - S / 2);
    int    M  = 2 * N6 + 2 * N8;

    float* out  = (float*)d_out;
    float* out6 = out;                          // (N6, 2, 128)
    float* out8 = out + (size_t)N6 * 256;       // (N8, 2, 128)
    float* nt6  = out + (size_t)(N6 + N8) * 256;
    float* nt8  = nt6 + N6;

    int* base = (int*)d_ws;                     // [M]
    int* bsum = base + M;                       // [MAXB]
    int* csr  = bsum + MAXB;                    // [Etot]

    int NB = (M + EPB - 1) / EPB;               // scan chunks (M=400K -> 391)

    hipMemsetAsync(base, 0, (size_t)M * sizeof(int), stream);

    int eg = (Etot + 255) / 256;
    if (eg > 4096) eg = 4096;
    count_kernel<<<dim3(eg), dim3(256), 0, stream>>>(
        ei66, ei86, ei68, ei88, E66, E86, E68, E88, N6, N8, base);

    scan1_kernel<<<dim3(NB), dim3(256), 0, stream>>>(base, M, bsum);
    scan2_kernel<<<dim3(1),  dim3(256), 0, stream>>>(bsum, NB);
    scan3_kernel<<<dim3(NB), dim3(256), 0, stream>>>(base, M, bsum);

    fill_kernel<<<dim3(eg), dim3(256), 0, stream>>>(
        ei66, ei86, ei68, ei88, E66, E86, E68, E88, N6, N8, base, csr);

    int eb66 = 0, eb86 = E66, eb68 = E66 + E86, eb88 = E66 + E86 + E68;
    dim3 b(256);
    dim3 g6((N6 + TB - 1) / TB), g8((N8 + TB - 1) / TB);
    gather_mfma_kernel<<<g6, b, 0, stream>>>(msg66, W66, base, csr, 0,           eb66, out6,       N6);
    gather_mfma_kernel<<<g6, b, 0, stream>>>(msg86, W86, base, csr, N6,          eb86, out6 + 128, N6);
    gather_mfma_kernel<<<g8, b, 0, stream>>>(msg68, W68, base, csr, 2 * N6,      eb68, out8,       N8);
    gather_mfma_kernel<<<g8, b, 0, stream>>>(msg88, W88, base, csr, 2 * N6 + N8, eb88, out8 + 128, N8);

    int Nmax = (N6 > N8) ? N6 : N8;
    mask_kernel<<<dim3((Nmax + 255) / 256), dim3(256), 0, stream>>>(
        base, nt6, nt8, N6, N8);
}

// Round 6
// 757.752 us; speedup vs baseline: 1.2893x; 1.2893x over previous
//
#include <hip/hip_runtime.h>

#define DF   128    // feature dim
#define EPB  1024   // elements per scan block
#define MAXB 512    // max level-2 scan width (supports M <= 524288)
#define TPB  64     // nodes per block-tile (4 waves x 16 rows)

typedef __attribute__((ext_vector_type(8))) short short8;
typedef __attribute__((ext_vector_type(4))) float f32x4;

__device__ __forceinline__ unsigned short f2bf(float x) {
    unsigned u = __float_as_uint(x);
    u = (u + 0x7FFFu + ((u >> 16) & 1u)) >> 16;   // RNE
    return (unsigned short)u;
}
__device__ __forceinline__ unsigned pack2bf(float a, float b) {
    return (unsigned)f2bf(a) | ((unsigned)f2bf(b) << 16);
}

// ===========================================================================
// CSR build: count degrees -> exclusive scan -> place edge ids.
// Node space M = [66: 0..N6) [86: N6..2N6) [68: 2N6..2N6+N8) [88: ...+N8)
// Edge space  = [66: 0..E66) [86 ...) [68 ...) [88 ...)  (global gid)
// ===========================================================================

__global__ void __launch_bounds__(256) count_kernel(
    const int* __restrict__ ei66, const int* __restrict__ ei86,
    const int* __restrict__ ei68, const int* __restrict__ ei88,
    int E66, int E86, int E68, int E88, int N6, int N8,
    int* __restrict__ base)
{
    int Etot = E66 + E86 + E68 + E88;
    for (int gid = blockIdx.x * 256 + threadIdx.x; gid < Etot;
         gid += gridDim.x * 256) {
        int le = gid, nb, dst;
        if (le < E66)               { dst = ei66[2 * le + 1]; nb = 0; }
        else if ((le -= E66) < E86) { dst = ei86[2 * le + 1]; nb = N6; }
        else if ((le -= E86) < E68) { dst = ei68[2 * le + 1]; nb = 2 * N6; }
        else { le -= E68;             dst = ei88[2 * le + 1]; nb = 2 * N6 + N8; }
        atomicAdd(base + nb + dst, 1);
    }
}

__global__ void __launch_bounds__(256) scan1_kernel(
    int* __restrict__ data, int M, int* __restrict__ bsum)
{
    __shared__ int ts[256];
    int t = threadIdx.x;
    int i0 = blockIdx.x * EPB + t * 4;
    int v0 = 0, v1 = 0, v2 = 0, v3 = 0;
    if (i0 + 3 < M) {
        int4 q = *(const int4*)(data + i0);
        v0 = q.x; v1 = q.y; v2 = q.z; v3 = q.w;
    } else {
        if (i0     < M) v0 = data[i0];
        if (i0 + 1 < M) v1 = data[i0 + 1];
        if (i0 + 2 < M) v2 = data[i0 + 2];
    }
    int sum = v0 + v1 + v2 + v3;
    ts[t] = sum;
    __syncthreads();
    for (int off = 1; off < 256; off <<= 1) {
        int x = (t >= off) ? ts[t - off] : 0;
        __syncthreads();
        ts[t] += x;
        __syncthreads();
    }
    int excl = ts[t] - sum;
    if (t == 255) bsum[blockIdx.x] = ts[255];
    int w0 = excl, w1 = excl + v0, w2 = w1 + v1, w3 = w2 + v2;
    if (i0 + 3 < M) {
        *(int4*)(data + i0) = make_int4(w0, w1, w2, w3);
    } else {
        if (i0     < M) data[i0]     = w0;
        if (i0 + 1 < M) data[i0 + 1] = w1;
        if (i0 + 2 < M) data[i0 + 2] = w2;
    }
}

__global__ void __launch_bounds__(256) scan2_kernel(int* __restrict__ bsum, int nb)
{
    __shared__ int s[MAXB];
    int t = threadIdx.x;
    s[t]       = (t       < nb) ? bsum[t]       : 0;
    s[t + 256] = (t + 256 < nb) ? bsum[t + 256] : 0;
    __syncthreads();
    int o0 = s[t], o1 = s[t + 256];
    for (int off = 1; off < MAXB; off <<= 1) {
        int a = (t       >= off) ? s[t       - off] : 0;
        int b = (t + 256 >= off) ? s[t + 256 - off] : 0;
        __syncthreads();
        s[t] += a; s[t + 256] += b;
        __syncthreads();
    }
    if (t       < nb) bsum[t]       = s[t]       - o0;
    if (t + 256 < nb) bsum[t + 256] = s[t + 256] - o1;
}

__global__ void __launch_bounds__(256) scan3_kernel(
    int* __restrict__ data, int M, const int* __restrict__ bsum)
{
    int add = bsum[blockIdx.x];
    if (add == 0) return;
    int i0 = blockIdx.x * EPB + threadIdx.x * 4;
    if (i0 + 3 < M) {
        int4 q = *(const int4*)(data + i0);
        q.x += add; q.y += add; q.z += add; q.w += add;
        *(int4*)(data + i0) = q;
    } else {
        if (i0     < M) data[i0]     += add;
        if (i0 + 1 < M) data[i0 + 1] += add;
        if (i0 + 2 < M) data[i0 + 2] += add;
    }
}

__global__ void __launch_bounds__(256) fill_kernel(
    const int* __restrict__ ei66, const int* __restrict__ ei86,
    const int* __restrict__ ei68, const int* __restrict__ ei88,
    int E66, int E86, int E68, int E88, int N6, int N8,
    int* __restrict__ base, int* __restrict__ csr)
{
    int Etot = E66 + E86 + E68 + E88;
    for (int gid = blockIdx.x * 256 + threadIdx.x; gid < Etot;
         gid += gridDim.x * 256) {
        int le = gid, nb, dst;
        if (le < E66)               { dst = ei66[2 * le + 1]; nb = 0; }
        else if ((le -= E66) < E86) { dst = ei86[2 * le + 1]; nb = N6; }
        else if ((le -= E86) < E68) { dst = ei68[2 * le + 1]; nb = 2 * N6; }
        else { le -= E68;             dst = ei88[2 * le + 1]; nb = 2 * N6 + N8; }
        int pos = atomicAdd(base + nb + dst, 1);
        csr[pos] = gid;
    }
}

// ===========================================================================
// Fused kernel: r4's pipelined 8-stream gather (2 rounds -> 16 rows/wave,
// mean folded into bf16 flush) + MFMA projection from per-wave LDS A-tiles.
// W^T staged bf16+swizzled once per block; A-tiles are wave-private so the
// tile loop needs NO block barrier. LDS = 32K (Wt) + 16K (At) = 48 KB.
// Swizzle: element k of row m lives at short index
//   m*DF + ((k>>3) ^ (m&7))*8 + (k&7)     (16B-chunk XOR swizzle)
// After fill: start(g) = g ? base[g-1] : 0, end(g) = base[g] (cumulative).
// ===========================================================================
__global__ void __launch_bounds__(256, 3) gather_mfma_kernel(
    const float* __restrict__ msg, const float* __restrict__ Wm,
    const int* __restrict__ base, const int* __restrict__ csr,
    int gbase, int ebase, float* __restrict__ out, int N, int ntiles)
{
    __shared__ alignas(16) short Wt[DF * DF];      // 32 KB bf16 W^T (swizzled)
    __shared__ alignas(16) short At[4][16 * DF];   // 16 KB, 16 rows per wave

    const int t    = threadIdx.x;
    const int lane = t & 63;
    const int w    = t >> 6;

    // ---- stage W^T once: row n holds W[k][n] along k (bf16, swizzled) ----
    // k-pair packing -> 4-byte LDS writes.
    for (int idx = t; idx < 2048; idx += 256) {
        int kp = idx >> 5;               // k-pair id 0..63
        int ng = (idx & 31) << 2;        // n group base 0,4,..,124
        int k0 = kp << 1;
        float4 wa = *(const float4*)(Wm + (size_t)k0 * DF + ng);
        float4 wb = *(const float4*)(Wm + (size_t)(k0 + 1) * DF + ng);
        float wav[4] = {wa.x, wa.y, wa.z, wa.w};
        float wbv[4] = {wb.x, wb.y, wb.z, wb.w};
        int cb = k0 >> 3, kl = k0 & 7;
        #pragma unroll
        for (int j = 0; j < 4; ++j) {
            int n = ng + j;
            int chunk = cb ^ (n & 7);
            *(unsigned*)(Wt + n * DF + chunk * 8 + kl) = pack2bf(wav[j], wbv[j]);
        }
    }
    __syncthreads();

    const int l15 = lane & 15;
    const int lg  = lane >> 4;

    for (int tile = blockIdx.x; tile < ntiles; tile += gridDim.x) {
        const int n0 = tile * TPB;

        // ---------------- gather: 2 rounds x 8 pipelined streams ----------
        #pragma unroll 1
        for (int rd = 0; rd < 2; ++rd) {
            const int lr0 = rd * 8;                 // local rows lr0..lr0+7
            int st8[8], en8[8];
            #pragma unroll
            for (int r = 0; r < 8; ++r) {
                int n = n0 + w * 16 + lr0 + r;
                if (n < N) {
                    int g = gbase + n;
                    st8[r] = g ? base[g - 1] : 0;
                    en8[r] = base[g];
                } else { st8[r] = 0; en8[r] = 0; }
            }

            float2 a[8], v[8];
            int eid[8], eidn[8], ptr2[8];
            bool any = false;
            #pragma unroll
            for (int r = 0; r < 8; ++r) {
                a[r]   = make_float2(0.f, 0.f);
                eid[r] = (st8[r] < en8[r]) ? csr[st8[r]] : -1;
                any |= (eid[r] >= 0);
            }
            #pragma unroll
            for (int r = 0; r < 8; ++r)
                eidn[r] = (st8[r] + 1 < en8[r]) ? csr[st8[r] + 1] : -1;
            #pragma unroll
            for (int r = 0; r < 8; ++r) {
                ptr2[r] = st8[r] + 2;
                v[r] = (eid[r] >= 0)
                    ? ((const float2*)(msg + (size_t)(eid[r] - ebase) * DF))[lane]
                    : make_float2(0.f, 0.f);
            }

            while (any) {
                int eidn2[8];
                #pragma unroll
                for (int r = 0; r < 8; ++r) {
                    bool f = (eidn[r] >= 0) && (ptr2[r] < en8[r]);
                    eidn2[r] = f ? csr[ptr2[r]] : -1;
                    ptr2[r] += f ? 1 : 0;
                }
                float2 vn[8];
                #pragma unroll
                for (int r = 0; r < 8; ++r)
                    vn[r] = (eidn[r] >= 0)
                        ? ((const float2*)(msg + (size_t)(eidn[r] - ebase) * DF))[lane]
                        : make_float2(0.f, 0.f);
                any = false;
                #pragma unroll
                for (int r = 0; r < 8; ++r) {
                    if (eid[r] >= 0) { a[r].x += v[r].x; a[r].y += v[r].y; }
                    eid[r]  = eidn[r];
                    v[r]    = vn[r];
                    eidn[r] = eidn2[r];
                    any |= (eid[r] >= 0);
                }
            }

            // flush (mean folded): lane owns feature cols 2*lane, 2*lane+1
            #pragma unroll
            for (int r = 0; r < 8; ++r) {
                int  lr  = lr0 + r;
                int  deg = en8[r] - st8[r];
                float inv = (deg > 0) ? (1.0f / (float)deg) : 0.0f;
                *(unsigned*)(At[w] + lr * DF + (((lane >> 2) ^ (lr & 7)) << 3)
                             + ((lane & 3) << 1))
                    = pack2bf(a[r].x * inv, a[r].y * inv);
            }
        }

        // ---------------- MFMA: wave's 16 rows x 128 cols ------------------
        // A(m,k): m=lane&15, k=(lane>>4)*8+j ; B(k,n): n=lane&15, same k.
        // D: col=lane&15, row=(lane>>4)*4+reg.
        f32x4 acc[8];
        #pragma unroll
        for (int j = 0; j < 8; ++j) acc[j] = (f32x4){0.f, 0.f, 0.f, 0.f};

        #pragma unroll
        for (int kk = 0; kk < 4; ++kk) {
            int c = kk * 4 + lg;
            short8 av = *(const short8*)(At[w] + l15 * DF
                                         + ((c ^ (l15 & 7)) << 3));
            #pragma unroll
            for (int j = 0; j < 8; ++j) {
                int n = j * 16 + l15;
                short8 bv = *(const short8*)(Wt + n * DF + ((c ^ (n & 7)) << 3));
                acc[j] = __builtin_amdgcn_mfma_f32_16x16x32_bf16(
                    av, bv, acc[j], 0, 0, 0);
            }
        }

        // ---------------- store ----------------
        #pragma unroll
        for (int q = 0; q < 4; ++q) {
            int lr   = lg * 4 + q;
            int node = n0 + w * 16 + lr;
            if (node < N) {
                float* op = out + (size_t)node * 256;
                #pragma unroll
                for (int j = 0; j < 8; ++j)
                    op[j * 16 + l15] = acc[j][q];
            }
        }
    }
}

// masks from post-fill base diffs: num_types = (deg_a>0) + (deg_b>0)
__global__ void __launch_bounds__(256) mask_kernel(
    const int* __restrict__ base, float* __restrict__ nt6,
    float* __restrict__ nt8, int N6, int N8)
{
    int i = blockIdx.x * blockDim.x + threadIdx.x;
    if (i < N6) {
        int g66 = i, g86 = N6 + i;
        int d66 = base[g66] - (g66 ? base[g66 - 1] : 0);
        int d86 = base[g86] - base[g86 - 1];
        nt6[i] = (float)((d66 > 0) + (d86 > 0));
    }
    if (i < N8) {
        int g68 = 2 * N6 + i, g88 = 2 * N6 + N8 + i;
        int d68 = base[g68] - base[g68 - 1];
        int d88 = base[g88] - base[g88 - 1];
        nt8[i] = (float)((d68 > 0) + (d88 > 0));
    }
}

extern "C" void kernel_launch(void* const* d_in, const int* in_sizes, int n_in,
                              void* d_out, int out_size, void* d_ws, size_t ws_size,
                              hipStream_t stream)
{
    const float* msg66 = (const float*)d_in[0];
    const float* msg68 = (const float*)d_in[1];
    const float* msg86 = (const float*)d_in[2];
    const float* msg88 = (const float*)d_in[3];
    const float* W66   = (const float*)d_in[4];
    const float* W68   = (const float*)d_in[5];
    const float* W86   = (const float*)d_in[6];
    const float* W88   = (const float*)d_in[7];
    const int*   ei66  = (const int*)d_in[8];
    const int*   ei68  = (const int*)d_in[9];
    const int*   ei86  = (const int*)d_in[10];
    const int*   ei88  = (const int*)d_in[11];

    int E66 = in_sizes[8]  / 2;
    int E68 = in_sizes[9]  / 2;
    int E86 = in_sizes[10] / 2;
    int E88 = in_sizes[11] / 2;
    int Etot = E66 + E86 + E68 + E88;

    size_t S  = (size_t)out_size / 257;       // out = 257*(N6+N8)
    int    N6 = (int)(S / 2);
    int    N8 = (int)(S - S / 2);
    int    M  = 2 * N6 + 2 * N8;

    float* out  = (float*)d_out;
    float* out6 = out;                          // (N6, 2, 128)
    float* out8 = out + (size_t)N6 * 256;       // (N8, 2, 128)
    float* nt6  = out + (size_t)(N6 + N8) * 256;
    float* nt8  = nt6 + N6;

    int* base = (int*)d_ws;                     // [M]
    int* bsum = base + M;                       // [MAXB]
    int* csr  = bsum + MAXB;                    // [Etot]

    int NB = (M + EPB - 1) / EPB;               // scan chunks (M=400K -> 391)

    hipMemsetAsync(base, 0, (size_t)M * sizeof(int), stream);

    int eg = (Etot + 255) / 256;
    if (eg > 4096) eg = 4096;
    count_kernel<<<dim3(eg), dim3(256), 0, stream>>>(
        ei66, ei86, ei68, ei88, E66, E86, E68, E88, N6, N8, base);

    scan1_kernel<<<dim3(NB), dim3(256), 0, stream>>>(base, M, bsum);
    scan2_kernel<<<dim3(1),  dim3(256), 0, stream>>>(bsum, NB);
    scan3_kernel<<<dim3(NB), dim3(256), 0, stream>>>(base, M, bsum);

    fill_kernel<<<dim3(eg), dim3(256), 0, stream>>>(
        ei66, ei86, ei68, ei88, E66, E86, E68, E88, N6, N8, base, csr);

    int eb66 = 0, eb86 = E66, eb68 = E66 + E86, eb88 = E66 + E86 + E68;

    int t6 = (N6 + TPB - 1) / TPB, t8 = (N8 + TPB - 1) / TPB;
    dim3 b(256), g6((t6 + 1) / 2), g8((t8 + 1) / 2);   // ~2 tiles per block
    gather_mfma_kernel<<<g6, b, 0, stream>>>(msg66, W66, base, csr, 0,           eb66, out6,       N6, t6);
    gather_mfma_kernel<<<g6, b, 0, stream>>>(msg86, W86, base, csr, N6,          eb86, out6 + 128, N6, t6);
    gather_mfma_kernel<<<g8, b, 0, stream>>>(msg68, W68, base, csr, 2 * N6,      eb68, out8,       N8, t8);
    gather_mfma_kernel<<<g8, b, 0, stream>>>(msg88, W88, base, csr, 2 * N6 + N8, eb88, out8 + 128, N8, t8);

    int Nmax = (N6 > N8) ? N6 : N8;
    mask_kernel<<<dim3((Nmax + 255) / 256), dim3(256), 0, stream>>>(
        base, nt6, nt8, N6, N8);
}

// Round 7
// 608.992 us; speedup vs baseline: 1.6043x; 1.2443x over previous
//
#include <hip/hip_runtime.h>

#define DF   128    // feature dim
#define EPB  1024   // elements per scan block
#define MAXB 512    // max level-2 scan width (supports M <= 524288)
#define TPB  64     // nodes per block-tile (4 waves x 16 rows)
#define WST  136    // padded LDS row stride in shorts (128 + 8)

typedef __attribute__((ext_vector_type(8))) short short8;
typedef __attribute__((ext_vector_type(4))) float f32x4;

__device__ __forceinline__ unsigned short f2bf(float x) {
    unsigned u = __float_as_uint(x);
    u = (u + 0x7FFFu + ((u >> 16) & 1u)) >> 16;   // RNE
    return (unsigned short)u;
}
__device__ __forceinline__ unsigned pack2bf(float a, float b) {
    return (unsigned)f2bf(a) | ((unsigned)f2bf(b) << 16);
}

// ===========================================================================
// CSR build: count degrees -> exclusive scan -> place edge ids.
// Node space M = [66: 0..N6) [86: N6..2N6) [68: 2N6..2N6+N8) [88: ...+N8)
// Edge space  = [66: 0..E66) [86 ...) [68 ...) [88 ...)  (global gid)
// ===========================================================================

__global__ void __launch_bounds__(256) count_kernel(
    const int* __restrict__ ei66, const int* __restrict__ ei86,
    const int* __restrict__ ei68, const int* __restrict__ ei88,
    int E66, int E86, int E68, int E88, int N6, int N8,
    int* __restrict__ base)
{
    int Etot = E66 + E86 + E68 + E88;
    for (int gid = blockIdx.x * 256 + threadIdx.x; gid < Etot;
         gid += gridDim.x * 256) {
        int le = gid, nb, dst;
        if (le < E66)               { dst = ei66[2 * le + 1]; nb = 0; }
        else if ((le -= E66) < E86) { dst = ei86[2 * le + 1]; nb = N6; }
        else if ((le -= E86) < E68) { dst = ei68[2 * le + 1]; nb = 2 * N6; }
        else { le -= E68;             dst = ei88[2 * le + 1]; nb = 2 * N6 + N8; }
        atomicAdd(base + nb + dst, 1);
    }
}

__global__ void __launch_bounds__(256) scan1_kernel(
    int* __restrict__ data, int M, int* __restrict__ bsum)
{
    __shared__ int ts[256];
    int t = threadIdx.x;
    int i0 = blockIdx.x * EPB + t * 4;
    int v0 = 0, v1 = 0, v2 = 0, v3 = 0;
    if (i0 + 3 < M) {
        int4 q = *(const int4*)(data + i0);
        v0 = q.x; v1 = q.y; v2 = q.z; v3 = q.w;
    } else {
        if (i0     < M) v0 = data[i0];
        if (i0 + 1 < M) v1 = data[i0 + 1];
        if (i0 + 2 < M) v2 = data[i0 + 2];
    }
    int sum = v0 + v1 + v2 + v3;
    ts[t] = sum;
    __syncthreads();
    for (int off = 1; off < 256; off <<= 1) {
        int x = (t >= off) ? ts[t - off] : 0;
        __syncthreads();
        ts[t] += x;
        __syncthreads();
    }
    int excl = ts[t] - sum;
    if (t == 255) bsum[blockIdx.x] = ts[255];
    int w0 = excl, w1 = excl + v0, w2 = w1 + v1, w3 = w2 + v2;
    if (i0 + 3 < M) {
        *(int4*)(data + i0) = make_int4(w0, w1, w2, w3);
    } else {
        if (i0     < M) data[i0]     = w0;
        if (i0 + 1 < M) data[i0 + 1] = w1;
        if (i0 + 2 < M) data[i0 + 2] = w2;
    }
}

__global__ void __launch_bounds__(256) scan2_kernel(int* __restrict__ bsum, int nb)
{
    __shared__ int s[MAXB];
    int t = threadIdx.x;
    s[t]       = (t       < nb) ? bsum[t]       : 0;
    s[t + 256] = (t + 256 < nb) ? bsum[t + 256] : 0;
    __syncthreads();
    int o0 = s[t], o1 = s[t + 256];
    for (int off = 1; off < MAXB; off <<= 1) {
        int a = (t       >= off) ? s[t       - off] : 0;
        int b = (t + 256 >= off) ? s[t + 256 - off] : 0;
        __syncthreads();
        s[t] += a; s[t + 256] += b;
        __syncthreads();
    }
    if (t       < nb) bsum[t]       = s[t]       - o0;
    if (t + 256 < nb) bsum[t + 256] = s[t + 256] - o1;
}

__global__ void __launch_bounds__(256) scan3_kernel(
    int* __restrict__ data, int M, const int* __restrict__ bsum)
{
    int add = bsum[blockIdx.x];
    if (add == 0) return;
    int i0 = blockIdx.x * EPB + threadIdx.x * 4;
    if (i0 + 3 < M) {
        int4 q = *(const int4*)(data + i0);
        q.x += add; q.y += add; q.z += add; q.w += add;
        *(int4*)(data + i0) = q;
    } else {
        if (i0     < M) data[i0]     += add;
        if (i0 + 1 < M) data[i0 + 1] += add;
        if (i0 + 2 < M) data[i0 + 2] += add;
    }
}

__global__ void __launch_bounds__(256) fill_kernel(
    const int* __restrict__ ei66, const int* __restrict__ ei86,
    const int* __restrict__ ei68, const int* __restrict__ ei88,
    int E66, int E86, int E68, int E88, int N6, int N8,
    int* __restrict__ base, int* __restrict__ csr)
{
    int Etot = E66 + E86 + E68 + E88;
    for (int gid = blockIdx.x * 256 + threadIdx.x; gid < Etot;
         gid += gridDim.x * 256) {
        int le = gid, nb, dst;
        if (le < E66)               { dst = ei66[2 * le + 1]; nb = 0; }
        else if ((le -= E66) < E86) { dst = ei86[2 * le + 1]; nb = N6; }
        else if ((le -= E86) < E68) { dst = ei68[2 * le + 1]; nb = 2 * N6; }
        else { le -= E68;             dst = ei88[2 * le + 1]; nb = 2 * N6 + N8; }
        int pos = atomicAdd(base + nb + dst, 1);
        csr[pos] = gid;
    }
}

// ===========================================================================
// Fused kernel: flat pipelined CSR walk (dense slots, depth-2 msg / depth-3
// csr pipeline) -> bf16 LDS A-tile (mean folded) -> MFMA -> LDS-transpose
// coalesced float4 store.
// LDS swizzle: element k of row m at short idx m*WST + ((k>>3 + m)&15)*8 + (k&7).
// After fill: start(g) = g ? base[g-1] : 0, end(g) = base[g] (cumulative,
// GLOBAL across the 4 type regions -> csr slots are global indices).
// ===========================================================================
__global__ void __launch_bounds__(256, 2) gather_mfma_kernel(
    const float* __restrict__ msg, const float* __restrict__ Wm,
    const int* __restrict__ base, const int* __restrict__ csr,
    int gbase, int ebase, float* __restrict__ out, int N, int ntiles)
{
    __shared__ alignas(16) short Wt[DF * WST];     // 34 KB bf16 W^T (swizzled)
    __shared__ alignas(16) short At[4][16 * WST];  // 17 KB, 16 rows per wave

    const int t    = threadIdx.x;
    const int lane = t & 63;
    const int w    = t >> 6;

    // ---- stage W^T once: row n holds W[k][n] along k (bf16, swizzled) ----
    for (int idx = t; idx < 2048; idx += 256) {
        int kp = idx >> 5;               // k-pair id 0..63
        int ng = (idx & 31) << 2;        // n group base 0,4,..,124
        int k0 = kp << 1;
        float4 wa = *(const float4*)(Wm + (size_t)k0 * DF + ng);
        float4 wb = *(const float4*)(Wm + (size_t)(k0 + 1) * DF + ng);
        float wav[4] = {wa.x, wa.y, wa.z, wa.w};
        float wbv[4] = {wb.x, wb.y, wb.z, wb.w};
        int cb = k0 >> 3, kl = k0 & 7;
        #pragma unroll
        for (int j = 0; j < 4; ++j) {
            int n = ng + j;
            int loc = (cb + n) & 15;
            *(unsigned*)(Wt + n * WST + loc * 8 + kl) = pack2bf(wav[j], wbv[j]);
        }
    }
    __syncthreads();

    const int l15 = lane & 15;
    const int lg  = lane >> 4;
    short* Aw = At[w];

    for (int tile = blockIdx.x; tile < ntiles; tile += gridDim.x) {
        const int n0    = tile * TPB;
        const int wrow0 = w * 16;
        const int node0 = n0 + wrow0;

        // lane l (0..16) holds cumulative end for node node0+l-1
        int endsv = 0;
        {
            int nn = node0 + lane - 1;
            if (nn >= N) nn = N - 1;
            int idx = gbase + nn;
            if (lane <= 16) endsv = (idx >= 0) ? base[idx] : 0;
        }
        const int s0 = __shfl(endsv, 0);
        const int s1 = __shfl(endsv, 16);

        int  scur = s0, row = 0, stcur = s0;
        int  nend = __shfl(endsv, 1);
        float ax = 0.f, ay = 0.f;

        auto flush = [&]() {
            int   deg = nend - stcur;
            float inv = (deg > 0) ? (1.0f / (float)deg) : 0.0f;
            *(unsigned*)(Aw + row * WST + ((((lane >> 2) + row) & 15) << 3)
                         + ((lane & 3) << 1)) = pack2bf(ax * inv, ay * inv);
            ax = 0.f; ay = 0.f;
            ++row; stcur = nend;
            nend = (row < 16) ? __shfl(endsv, row + 1) : (int)0x80000000;
        };
        auto consume = [&](float2 (&v)[8], int bi) {
            #pragma unroll
            for (int j = 0; j < 8; ++j) {
                if (s0 + bi + j < s1) {
                    while (scur == nend) flush();
                    ax += v[j].x; ay += v[j].y; ++scur;
                }
            }
        };

        const int total = s1 - s0;
        const int nb = (total + 7) >> 3;

        int e0[8], e1[8], e2[8];
        float2 vA[8], vB[8];
        #pragma unroll
        for (int j = 0; j < 8; ++j) e0[j] = (s0 + j      < s1) ? csr[s0 + j]      : 0;
        #pragma unroll
        for (int j = 0; j < 8; ++j) e1[j] = (s0 + 8 + j  < s1) ? csr[s0 + 8 + j]  : 0;
        #pragma unroll
        for (int j = 0; j < 8; ++j) e2[j] = (s0 + 16 + j < s1) ? csr[s0 + 16 + j] : 0;
        #pragma unroll
        for (int j = 0; j < 8; ++j)
            vA[j] = (s0 + j < s1)
                ? ((const float2*)(msg + (size_t)(e0[j] - ebase) * DF))[lane]
                : make_float2(0.f, 0.f);

        int i = 0;
        // body(i): issue msg batch i+1 from e[(i+1)%3]; load csr batch i+3
        // into e[i%3]; consume msg batch i. Overshoot bodies are no-ops.
#define GB(vCons, vIss, eIss, eLd)  do {                                     \
        int b1 = (i + 1) << 3, b3 = (i + 3) << 3;                            \
        _Pragma("unroll")                                                    \
        for (int j = 0; j < 8; ++j)                                          \
            vIss[j] = (s0 + b1 + j < s1)                                     \
                ? ((const float2*)(msg + (size_t)(eIss[j] - ebase) * DF))[lane] \
                : make_float2(0.f, 0.f);                                     \
        _Pragma("unroll")                                                    \
        for (int j = 0; j < 8; ++j)                                          \
            eLd[j] = (s0 + b3 + j < s1) ? csr[s0 + b3 + j] : 0;              \
        consume(vCons, i << 3);                                              \
        ++i; } while (0)

        while (i < nb) {
            GB(vA, vB, e1, e0);
            GB(vB, vA, e2, e1);
            GB(vA, vB, e0, e2);
            GB(vB, vA, e1, e0);
            GB(vA, vB, e2, e1);
            GB(vB, vA, e0, e2);
        }
#undef GB
        while (row < 16) flush();

        // ---------------- MFMA: wave's 16 rows x 128 cols ------------------
        // A(m,k): m=lane&15, k=(lane>>4)*8+j ; B(k,n): n=lane&15, same k.
        // D: col=lane&15, row=(lane>>4)*4+reg.
        f32x4 acc[8];
        #pragma unroll
        for (int j = 0; j < 8; ++j) acc[j] = (f32x4){0.f, 0.f, 0.f, 0.f};

        #pragma unroll
        for (int kk = 0; kk < 4; ++kk) {
            int c = kk * 4 + lg;
            short8 av = *(const short8*)(Aw + l15 * WST + (((c + l15) & 15) << 3));
            #pragma unroll
            for (int j = 0; j < 8; ++j) {
                int n = j * 16 + l15;
                short8 bv = *(const short8*)(Wt + n * WST + (((c + n) & 15) << 3));
                acc[j] = __builtin_amdgcn_mfma_f32_16x16x32_bf16(
                    av, bv, acc[j], 0, 0, 0);
            }
        }

        // ------------- store: LDS transpose -> coalesced float4 -----------
        float* fA = (float*)Aw;          // 8 rows x 128 f32 per half
        #pragma unroll
        for (int h = 0; h < 2; ++h) {
            if ((lg >> 1) == h) {
                int lr = (lg & 1) << 2;
                #pragma unroll
                for (int q = 0; q < 4; ++q)
                    #pragma unroll
                    for (int j = 0; j < 8; ++j)
                        fA[(lr + q) * DF + j * 16 + l15] = acc[j][q];
            }
            asm volatile("" ::: "memory");
            #pragma unroll
            for (int rr = 0; rr < 4; ++rr) {
                int lrh  = 2 * rr + (lane >> 5);
                int node = node0 + 8 * h + lrh;
                float4 x = *(const float4*)(fA + lrh * DF + (lane & 31) * 4);
                if (node < N)
                    *(float4*)(out + (size_t)node * 256 + (lane & 31) * 4) = x;
            }
            asm volatile("" ::: "memory");
        }
    }
}

// masks from post-fill base diffs: num_types = (deg_a>0) + (deg_b>0)
__global__ void __launch_bounds__(256) mask_kernel(
    const int* __restrict__ base, float* __restrict__ nt6,
    float* __restrict__ nt8, int N6, int N8)
{
    int i = blockIdx.x * blockDim.x + threadIdx.x;
    if (i < N6) {
        int g66 = i, g86 = N6 + i;
        int d66 = base[g66] - (g66 ? base[g66 - 1] : 0);
        int d86 = base[g86] - base[g86 - 1];
        nt6[i] = (float)((d66 > 0) + (d86 > 0));
    }
    if (i < N8) {
        int g68 = 2 * N6 + i, g88 = 2 * N6 + N8 + i;
        int d68 = base[g68] - base[g68 - 1];
        int d88 = base[g88] - base[g88 - 1];
        nt8[i] = (float)((d68 > 0) + (d88 > 0));
    }
}

extern "C" void kernel_launch(void* const* d_in, const int* in_sizes, int n_in,
                              void* d_out, int out_size, void* d_ws, size_t ws_size,
                              hipStream_t stream)
{
    const float* msg66 = (const float*)d_in[0];
    const float* msg68 = (const float*)d_in[1];
    const float* msg86 = (const float*)d_in[2];
    const float* msg88 = (const float*)d_in[3];
    const float* W66   = (const float*)d_in[4];
    const float* W68   = (const float*)d_in[5];
    const float* W86   = (const float*)d_in[6];
    const float* W88   = (const float*)d_in[7];
    const int*   ei66  = (const int*)d_in[8];
    const int*   ei68  = (const int*)d_in[9];
    const int*   ei86  = (const int*)d_in[10];
    const int*   ei88  = (const int*)d_in[11];

    int E66 = in_sizes[8]  / 2;
    int E68 = in_sizes[9]  / 2;
    int E86 = in_sizes[10] / 2;
    int E88 = in_sizes[11] / 2;
    int Etot = E66 + E86 + E68 + E88;

    size_t S  = (size_t)out_size / 257;       // out = 257*(N6+N8)
    int    N6 = (int)(S / 2);
    int    N8 = (int)(S - S / 2);
    int    M  = 2 * N6 + 2 * N8;

    float* out  = (float*)d_out;
    float* out6 = out;                          // (N6, 2, 128)
    float* out8 = out + (size_t)N6 * 256;       // (N8, 2, 128)
    float* nt6  = out + (size_t)(N6 + N8) * 256;
    float* nt8  = nt6 + N6;

    int* base = (int*)d_ws;                     // [M]
    int* bsum = base + M;                       // [MAXB]
    int* csr  = bsum + MAXB;                    // [Etot]

    int NB = (M + EPB - 1) / EPB;               // scan chunks (M=400K -> 391)

    hipMemsetAsync(base, 0, (size_t)M * sizeof(int), stream);

    int eg = (Etot + 255) / 256;
    if (eg > 4096) eg = 4096;
    count_kernel<<<dim3(eg), dim3(256), 0, stream>>>(
        ei66, ei86, ei68, ei88, E66, E86, E68, E88, N6, N8, base);

    scan1_kernel<<<dim3(NB), dim3(256), 0, stream>>>(base, M, bsum);
    scan2_kernel<<<dim3(1),  dim3(256), 0, stream>>>(bsum, NB);
    scan3_kernel<<<dim3(NB), dim3(256), 0, stream>>>(base, M, bsum);

    fill_kernel<<<dim3(eg), dim3(256), 0, stream>>>(
        ei66, ei86, ei68, ei88, E66, E86, E68, E88, N6, N8, base, csr);

    int eb66 = 0, eb86 = E66, eb68 = E66 + E86, eb88 = E66 + E86 + E68;

    int t6 = (N6 + TPB - 1) / TPB, t8 = (N8 + TPB - 1) / TPB;
    dim3 b(256), g6((t6 + 1) / 2), g8((t8 + 1) / 2);   // ~2 tiles per block
    gather_mfma_kernel<<<g6, b, 0, stream>>>(msg66, W66, base, csr, 0,           eb66, out6,       N6, t6);
    gather_mfma_kernel<<<g6, b, 0, stream>>>(msg86, W86, base, csr, N6,          eb86, out6 + 128, N6, t6);
    gather_mfma_kernel<<<g8, b, 0, stream>>>(msg68, W68, base, csr, 2 * N6,      eb68, out8,       N8, t8);
    gather_mfma_kernel<<<g8, b, 0, stream>>>(msg88, W88, base, csr, 2 * N6 + N8, eb88, out8 + 128, N8, t8);

    int Nmax = (N6 > N8) ? N6 : N8;
    mask_kernel<<<dim3((Nmax + 255) / 256), dim3(256), 0, stream>>>(
        base, nt6, nt8, N6, N8);
}